// Round 13
// baseline (77.506 us; speedup 1.0000x reference)
//
#include <hip/hip_runtime.h>
#include <hip/hip_bf16.h>

#define NROWS 4096
#define DIM   1024           // K elements; 512 B/row in fp4 (2 elems/byte)
#define ROWB  512            // bytes per row of xn
#define BT    256            // tile edge (256x256 per block)
#define BKE   256            // K elems per step (= 128 B/row staged)
#define BKB   128            // bytes per row per step
#define NKT   (DIM / BKE)    // 4 K-steps
#define NTB   (NROWS / BT)   // 16 tile-blocks per edge
#define TEMP_INV 10.0f
#define INV_S 9.765625e-4f   // 1/1024 (fp4 stored as 32*x; p = acc/32^2)
#define SCALE1 0x7F7F7F7F    // E8M0 1.0 in all 4 bytes (validated R11)

typedef float f32x4 __attribute__((ext_vector_type(4)));
typedef int   i32x8 __attribute__((ext_vector_type(8)));
typedef int   i32x4 __attribute__((ext_vector_type(4)));

__device__ __forceinline__ void gload16(const void* g, void* l) {
    __builtin_amdgcn_global_load_lds(
        (const __attribute__((address_space(1))) void*)g,
        (__attribute__((address_space(3))) void*)l, 16, 0, 0);
}

// e2m1 quantize, round-to-nearest (midpoint thresholds), values
// {0,.5,1,1.5,2,3,4,6}; code c in 0..7 is monotone == fp4 bit pattern.
__device__ __forceinline__ unsigned qfp4(float x) {
    const float m = fabsf(x);
    const unsigned c = (unsigned)(m >= 0.25f) + (unsigned)(m >= 0.75f)
                     + (unsigned)(m >= 1.25f) + (unsigned)(m >= 1.75f)
                     + (unsigned)(m >= 2.5f)  + (unsigned)(m >= 3.5f)
                     + (unsigned)(m >= 5.0f);
    return c | (x < 0.0f ? 8u : 0u);
}

// Row-normalize fp32 -> fp4 e2m1 scaled by 32 (unit-row rms -> 1.0, the
// sweet spot of e2m1's range); zeroes this row's partial accumulators.
// Natural k order, nibble-sequential packing (Gram is invariant to any
// shared A/B intra-block k-permutation, so packing convention is safe).
__global__ __launch_bounds__(256) void normalize_k(const float* __restrict__ pred,
                                                   unsigned short* __restrict__ xn,
                                                   float* __restrict__ posw,
                                                   float* __restrict__ denw) {
    const int row = blockIdx.x;
    const int tid = threadIdx.x;
    const float4 v = reinterpret_cast<const float4*>(pred + (size_t)row * DIM)[tid];
    float ss = v.x * v.x + v.y * v.y + v.z * v.z + v.w * v.w;
    #pragma unroll
    for (int off = 32; off; off >>= 1) ss += __shfl_xor(ss, off, 64);
    __shared__ float red[4];
    if ((tid & 63) == 0) red[tid >> 6] = ss;
    __syncthreads();
    const float tot = red[0] + red[1] + red[2] + red[3];
    const float scale = 32.0f / fmaxf(sqrtf(tot), 1e-8f);
    const unsigned q0 = qfp4(v.x * scale), q1 = qfp4(v.y * scale);
    const unsigned q2 = qfp4(v.z * scale), q3 = qfp4(v.w * scale);
    xn[row * (ROWB / 2) + tid] =
        (unsigned short)(q0 | (q1 << 4) | (q2 << 8) | (q3 << 12));
    if (tid == 0) { posw[row] = 0.0f; denw[row] = 0.0f; }
}

#define BAR asm volatile("s_barrier" ::: "memory")

// Stage one 256-row x 128-B fp4 K-chunk (32 KB) into LDS, 4 x gload16 per
// thread (512 thr).  R4/R9/R12's proven staging geometry byte-for-byte:
// linear LDS dest (m104), granule swizzle kg = (p&7)^(r&7) pre-applied on
// the global source (rule 21; 0 conflicts verified).
__device__ __forceinline__ void stage_tile(const unsigned char* __restrict__ src,
                                           unsigned char* lds, int tid) {
    #pragma unroll
    for (int c = 0; c < 4; ++c) {
        const int p  = c * 512 + tid;        // granule 0..2047
        const int r  = p >> 3;               // tile row 0..255
        const int kg = (p & 7) ^ (r & 7);    // logical k-granule held at p
        gload16(src + (size_t)r * ROWB + kg * 16, lds + p * 16);
    }
}

// Fused Gram-GEMM + contrastive epilogue.  Full 16x16 grid (256 blocks,
// 1/CU), 8 waves (2M x 4N), per-wave output 128x64.  R12's exact schedule
// (depth-2 counted vmcnt(8)), but fp4 operands: each 64 KB staged step now
// carries K=256 -> 4 steps instead of 8.  MFMA = mfma_scale 16x16x128
// f8f6f4 with cbsz=blgp=4 (fp4), scale=1.0.  Each lane's 32 k-values are
// one contiguous 16 B -> single conflict-free ds_read_b128; the 16 B is
// duplicated into both halves of the i32x8 operand so either 4-reg subset
// the HW reads for fp4 is correct.
__global__ __launch_bounds__(512, 2) void fused_gram(
        const unsigned short* __restrict__ xnu, const int* __restrict__ tgt,
        float* __restrict__ posw, float* __restrict__ denw) {
    __shared__ unsigned char As[2][BT * BKB];   // 2 x 32 KB
    __shared__ unsigned char Bs[2][BT * BKB];   // 2 x 32 KB  (128 KB total)

    const unsigned char* xn = (const unsigned char*)xnu;

    const int bi = blockIdx.x >> 4;
    const int bj = blockIdx.x & 15;
    const int rowbase = bi * BT;
    const int colbase = bj * BT;

    const int tid = threadIdx.x;
    const int w   = tid >> 6;
    const int l   = tid & 63;
    const int wr  = w >> 2;      // 0..1  (row half: 128 rows)
    const int wc  = w & 3;       // 0..3  (col quarter: 64 cols)
    const int l15 = l & 15;
    const int kgl = l >> 4;      // k-group 0..3 (32 k each per MFMA)

    const unsigned char* arow = xn + (size_t)rowbase * ROWB;
    const unsigned char* bcol = xn + (size_t)colbase * ROWB;

    // Per-lane LDS byte offsets.  MFMA m (k-base 128m) needs logical granule
    // m*4 + kgl of the lane's row; physical = logical ^ (row&7); row&7 ==
    // l15&7 for all our rows (wr/fi/wc/fj terms are multiples of 16).
    int rowA[8], rowB[4], xg[2];
    #pragma unroll
    for (int fi = 0; fi < 8; ++fi) rowA[fi] = (wr * 128 + fi * 16 + l15) * BKB;
    #pragma unroll
    for (int fj = 0; fj < 4; ++fj) rowB[fj] = (wc * 64 + fj * 16 + l15) * BKB;
    #pragma unroll
    for (int m = 0; m < 2; ++m) xg[m] = ((m * 4 + kgl) ^ (l15 & 7)) * 16;

    f32x4 acc[8][4];
    #pragma unroll
    for (int i = 0; i < 8; ++i)
        #pragma unroll
        for (int j = 0; j < 4; ++j)
            acc[i][j] = (f32x4){0.f, 0.f, 0.f, 0.f};

    // Prologue: stage K-chunk 0 into slot 0 (8 loads/thread).
    stage_tile(arow, &As[0][0], tid);
    stage_tile(bcol, &Bs[0][0], tid);

    for (int kt = 0; kt < NKT; ++kt) {
        const int cur = kt & 1;
        if (kt + 1 < NKT) {
            stage_tile(arow + (kt + 1) * BKB, &As[cur ^ 1][0], tid);
            stage_tile(bcol + (kt + 1) * BKB, &Bs[cur ^ 1][0], tid);
            asm volatile("s_waitcnt vmcnt(8)" ::: "memory");   // chunk kt landed
        } else {
            asm volatile("s_waitcnt vmcnt(0)" ::: "memory");
        }
        BAR;

        const unsigned char* as = &As[cur][0];
        const unsigned char* bs = &Bs[cur][0];
        #pragma unroll
        for (int m = 0; m < 2; ++m) {       // two K=128 MFMAs per staged chunk
            i32x8 a[8], b[4];
            #pragma unroll
            for (int fi = 0; fi < 8; ++fi) {
                const i32x4 p = *reinterpret_cast<const i32x4*>(&as[rowA[fi] + xg[m]]);
                i32x8 r; r[0]=p[0]; r[1]=p[1]; r[2]=p[2]; r[3]=p[3];
                         r[4]=p[0]; r[5]=p[1]; r[6]=p[2]; r[7]=p[3];
                a[fi] = r;
            }
            #pragma unroll
            for (int fj = 0; fj < 4; ++fj) {
                const i32x4 p = *reinterpret_cast<const i32x4*>(&bs[rowB[fj] + xg[m]]);
                i32x8 r; r[0]=p[0]; r[1]=p[1]; r[2]=p[2]; r[3]=p[3];
                         r[4]=p[0]; r[5]=p[1]; r[6]=p[2]; r[7]=p[3];
                b[fj] = r;
            }
            __builtin_amdgcn_s_setprio(1);
            #pragma unroll
            for (int fi = 0; fi < 8; ++fi)
                #pragma unroll
                for (int fj = 0; fj < 4; ++fj)
                    acc[fi][fj] = __builtin_amdgcn_mfma_scale_f32_16x16x128_f8f6f4(
                        a[fi], b[fj], acc[fi][fj],
                        4, 4,                 // cbsz = fp4(e2m1), blgp = fp4(e2m1)
                        0, SCALE1,            // opsel_a, scale_a = 1.0
                        0, SCALE1);           // opsel_b, scale_b = 1.0
            __builtin_amdgcn_s_setprio(0);
        }
        BAR;   // all reads of slot cur done before next iter overwrites it
    }

    // Fused epilogue (column-side only; full grid covers both (i,j),(j,i)).
    // 16x16 C/D layout: col = lane&15, row = (lane>>4)*4 + q.  p = acc/1024.
    int jc[4], tj[4];
    #pragma unroll
    for (int fj = 0; fj < 4; ++fj) {
        jc[fj] = colbase + wc * 64 + fj * 16 + l15;
        tj[fj] = tgt[jc[fj]];
    }
    float denc[4] = {0.f, 0.f, 0.f, 0.f};
    float posc[4] = {0.f, 0.f, 0.f, 0.f};

    #pragma unroll
    for (int fi = 0; fi < 8; ++fi) {
        const int ribase = rowbase + wr * 128 + fi * 16 + (l >> 4) * 4;
        const int4 tiv = *reinterpret_cast<const int4*>(&tgt[ribase]);
        const int tia[4] = {tiv.x, tiv.y, tiv.z, tiv.w};
        #pragma unroll
        for (int q = 0; q < 4; ++q) {
            const int gi = ribase + q;
            const int ti = tia[q];
            #pragma unroll
            for (int fj = 0; fj < 4; ++fj) {
                const float s  = acc[fi][fj][q] * INV_S;
                const float pc = fmaxf(s, 1e-10f);
                const float e  = __expf(TEMP_INV * pc);
                if (ti != tj[fj]) {
                    denc[fj] += e;
                } else if (gi != jc[fj]) {
                    posc[fj] += pc;
                }
            }
        }
    }

    // Lanes sharing a column differ in bits 4-5.
    #pragma unroll
    for (int fj = 0; fj < 4; ++fj) {
        #pragma unroll
        for (int off = 16; off < 64; off <<= 1) {
            denc[fj] += __shfl_xor(denc[fj], off, 64);
            posc[fj] += __shfl_xor(posc[fj], off, 64);
        }
        if (l < 16) {
            atomicAdd(&denw[jc[fj]], denc[fj]);
            atomicAdd(&posw[jc[fj]], posc[fj]);
        }
    }
}

// Single-block finalize: LDS class histogram + per-column loss + direct store.
__global__ __launch_bounds__(1024) void finalize_k(const float* __restrict__ posw,
                                                   const float* __restrict__ denw,
                                                   const int* __restrict__ tgt,
                                                   float* __restrict__ out) {
    __shared__ int hist[128];
    __shared__ float red[16];
    const int tid = threadIdx.x;
    if (tid < 128) hist[tid] = 0;
    __syncthreads();
    const int4 t4 = reinterpret_cast<const int4*>(tgt)[tid];   // 4 targets/thread
    atomicAdd(&hist[t4.x], 1);
    atomicAdd(&hist[t4.y], 1);
    atomicAdd(&hist[t4.z], 1);
    atomicAdd(&hist[t4.w], 1);
    __syncthreads();
    const int ta[4] = {t4.x, t4.y, t4.z, t4.w};
    float v = 0.0f;
    #pragma unroll
    for (int q = 0; q < 4; ++q) {
        const int j = tid * 4 + q;
        const float d = fmaxf(denw[j], 1e-10f);
        const float c = (float)(hist[ta[q]] - 1);
        v += TEMP_INV * posw[j] - c * __logf(d);
    }
    #pragma unroll
    for (int off = 32; off; off >>= 1) v += __shfl_xor(v, off, 64);
    if ((tid & 63) == 0) red[tid >> 6] = v;
    __syncthreads();
    if (tid == 0) {
        float s = 0.0f;
        #pragma unroll
        for (int i = 0; i < 16; ++i) s += red[i];
        out[0] = -s * (1.0f / 4096.0f);
    }
}

extern "C" void kernel_launch(void* const* d_in, const int* in_sizes, int n_in,
                              void* d_out, int out_size, void* d_ws, size_t ws_size,
                              hipStream_t stream) {
    const float* pred = (const float*)d_in[0];
    const int*   tgt  = (const int*)d_in[1];
    float* out = (float*)d_out;

    unsigned short* xn = (unsigned short*)d_ws;                      // 2 MB fp4
    float* posw = (float*)((char*)d_ws + (size_t)NROWS * ROWB);
    float* denw = posw + NROWS;

    normalize_k<<<NROWS, 256, 0, stream>>>(pred, xn, posw, denw);

    fused_gram<<<NTB * NTB, 512, 0, stream>>>(xn, tgt, posw, denw);  // 256 blocks

    finalize_k<<<1, 1024, 0, stream>>>(posw, denw, tgt, out);
}

// Round 14
// 73.336 us; speedup vs baseline: 1.0569x; 1.0569x over previous
//
#include <hip/hip_runtime.h>
#include <hip/hip_bf16.h>

#define NROWS 4096
#define DIM   1024           // K elements; 512 B/row in fp4 (2 elems/byte)
#define ROWB  512            // bytes per row of xn
#define BT    256            // tile edge (256x256 per block)
#define BKE   256            // K elems per step (= 128 B/row staged)
#define BKB   128            // bytes per row per step
#define NKT   (DIM / BKE)    // 4 K-steps
#define NTB   (NROWS / BT)   // 16 tile-blocks per edge
#define TEMP_INV 10.0f
#define INV_S 9.765625e-4f   // 1/1024 (fp4 stored as 32*x; p = acc/32^2)
#define SCALE1 0x7F7F7F7F    // E8M0 1.0 in all 4 bytes (validated R11/R13)

typedef float f32x4 __attribute__((ext_vector_type(4)));
typedef int   i32x8 __attribute__((ext_vector_type(8)));
typedef int   i32x4 __attribute__((ext_vector_type(4)));

__device__ __forceinline__ void gload16(const void* g, void* l) {
    __builtin_amdgcn_global_load_lds(
        (const __attribute__((address_space(1))) void*)g,
        (__attribute__((address_space(3))) void*)l, 16, 0, 0);
}

// e2m1 quantize, round-to-nearest (midpoint thresholds), values
// {0,.5,1,1.5,2,3,4,6}; code c in 0..7 is monotone == fp4 bit pattern.
// (Proven correct: R13 passed with absmax 0.0.)
__device__ __forceinline__ unsigned qfp4(float x) {
    const float m = fabsf(x);
    const unsigned c = (unsigned)(m >= 0.25f) + (unsigned)(m >= 0.75f)
                     + (unsigned)(m >= 1.25f) + (unsigned)(m >= 1.75f)
                     + (unsigned)(m >= 2.5f)  + (unsigned)(m >= 3.5f)
                     + (unsigned)(m >= 5.0f);
    return c | (x < 0.0f ? 8u : 0u);
}

// Row-normalize fp32 -> fp4 e2m1 scaled by 32; zeroes partial accumulators.
__global__ __launch_bounds__(256) void normalize_k(const float* __restrict__ pred,
                                                   unsigned short* __restrict__ xn,
                                                   float* __restrict__ posw,
                                                   float* __restrict__ denw) {
    const int row = blockIdx.x;
    const int tid = threadIdx.x;
    const float4 v = reinterpret_cast<const float4*>(pred + (size_t)row * DIM)[tid];
    float ss = v.x * v.x + v.y * v.y + v.z * v.z + v.w * v.w;
    #pragma unroll
    for (int off = 32; off; off >>= 1) ss += __shfl_xor(ss, off, 64);
    __shared__ float red[4];
    if ((tid & 63) == 0) red[tid >> 6] = ss;
    __syncthreads();
    const float tot = red[0] + red[1] + red[2] + red[3];
    const float scale = 32.0f / fmaxf(sqrtf(tot), 1e-8f);
    const unsigned q0 = qfp4(v.x * scale), q1 = qfp4(v.y * scale);
    const unsigned q2 = qfp4(v.z * scale), q3 = qfp4(v.w * scale);
    xn[row * (ROWB / 2) + tid] =
        (unsigned short)(q0 | (q1 << 4) | (q2 << 8) | (q3 << 12));
    if (tid == 0) { posw[row] = 0.0f; denw[row] = 0.0f; }
}

#define BAR asm volatile("s_barrier" ::: "memory")

// Stage one 256-row x 128-B fp4 K-chunk (32 KB) into LDS, 4 x gload16 per
// thread (512 thr).  Proven staging geometry: linear LDS dest (m104),
// granule swizzle kg = (p&7)^(r&7) pre-applied on the global source.
__device__ __forceinline__ void stage_tile(const unsigned char* __restrict__ src,
                                           unsigned char* lds, int tid) {
    #pragma unroll
    for (int c = 0; c < 4; ++c) {
        const int p  = c * 512 + tid;        // granule 0..2047
        const int r  = p >> 3;               // tile row 0..255
        const int kg = (p & 7) ^ (r & 7);    // logical k-granule held at p
        gload16(src + (size_t)r * ROWB + kg * 16, lds + p * 16);
    }
}

// Fused Gram-GEMM + contrastive epilogue.  R13's kernel (proven correct),
// register-pressure-fixed:
//   * __launch_bounds__(512, 1): hipcc's arg2 = blocks/CU (CUDA semantics);
//     R13's (512,2) capped VGPR at 128 -> acc spilled to scratch (FETCH
//     84 MB).  (512,1) gives the 256-VGPR budget; grid is 256 = 1/CU anyway.
//   * Inner loop split (b[4] hoisted per m; a processed 4-at-a-time) keeps
//     live regs ~210 < 256.
__global__ __launch_bounds__(512, 1) void fused_gram(
        const unsigned short* __restrict__ xnu, const int* __restrict__ tgt,
        float* __restrict__ posw, float* __restrict__ denw) {
    __shared__ unsigned char As[2][BT * BKB];   // 2 x 32 KB
    __shared__ unsigned char Bs[2][BT * BKB];   // 2 x 32 KB  (128 KB total)

    const unsigned char* xn = (const unsigned char*)xnu;

    const int bi = blockIdx.x >> 4;
    const int bj = blockIdx.x & 15;
    const int rowbase = bi * BT;
    const int colbase = bj * BT;

    const int tid = threadIdx.x;
    const int w   = tid >> 6;
    const int l   = tid & 63;
    const int wr  = w >> 2;      // 0..1  (row half: 128 rows)
    const int wc  = w & 3;       // 0..3  (col quarter: 64 cols)
    const int l15 = l & 15;
    const int kgl = l >> 4;      // k-group 0..3 (32 k each per MFMA)

    const unsigned char* arow = xn + (size_t)rowbase * ROWB;
    const unsigned char* bcol = xn + (size_t)colbase * ROWB;

    // Per-lane LDS byte offsets.  MFMA m (k-base 128m) needs logical granule
    // m*4 + kgl of the lane's row; physical = logical ^ (row&7); row&7 ==
    // l15&7 for all our rows.
    int rowA[8], rowB[4], xg[2];
    #pragma unroll
    for (int fi = 0; fi < 8; ++fi) rowA[fi] = (wr * 128 + fi * 16 + l15) * BKB;
    #pragma unroll
    for (int fj = 0; fj < 4; ++fj) rowB[fj] = (wc * 64 + fj * 16 + l15) * BKB;
    #pragma unroll
    for (int m = 0; m < 2; ++m) xg[m] = ((m * 4 + kgl) ^ (l15 & 7)) * 16;

    f32x4 acc[8][4];
    #pragma unroll
    for (int i = 0; i < 8; ++i)
        #pragma unroll
        for (int j = 0; j < 4; ++j)
            acc[i][j] = (f32x4){0.f, 0.f, 0.f, 0.f};

    // Prologue: stage K-chunk 0 into slot 0 (8 loads/thread).
    stage_tile(arow, &As[0][0], tid);
    stage_tile(bcol, &Bs[0][0], tid);

    for (int kt = 0; kt < NKT; ++kt) {
        const int cur = kt & 1;
        if (kt + 1 < NKT) {
            stage_tile(arow + (kt + 1) * BKB, &As[cur ^ 1][0], tid);
            stage_tile(bcol + (kt + 1) * BKB, &Bs[cur ^ 1][0], tid);
            asm volatile("s_waitcnt vmcnt(8)" ::: "memory");   // chunk kt landed
        } else {
            asm volatile("s_waitcnt vmcnt(0)" ::: "memory");
        }
        BAR;

        const unsigned char* as = &As[cur][0];
        const unsigned char* bs = &Bs[cur][0];
        #pragma unroll
        for (int m = 0; m < 2; ++m) {       // two K=128 MFMAs per staged chunk
            i32x8 b[4];
            #pragma unroll
            for (int fj = 0; fj < 4; ++fj) {
                const i32x4 p = *reinterpret_cast<const i32x4*>(&bs[rowB[fj] + xg[m]]);
                i32x8 r; r[0]=p[0]; r[1]=p[1]; r[2]=p[2]; r[3]=p[3];
                         r[4]=p[0]; r[5]=p[1]; r[6]=p[2]; r[7]=p[3];
                b[fj] = r;
            }
            #pragma unroll
            for (int fih = 0; fih < 8; fih += 4) {   // a 4-at-a-time: low pressure
                i32x8 a4[4];
                #pragma unroll
                for (int u = 0; u < 4; ++u) {
                    const i32x4 p = *reinterpret_cast<const i32x4*>(
                        &as[rowA[fih + u] + xg[m]]);
                    i32x8 r; r[0]=p[0]; r[1]=p[1]; r[2]=p[2]; r[3]=p[3];
                             r[4]=p[0]; r[5]=p[1]; r[6]=p[2]; r[7]=p[3];
                    a4[u] = r;
                }
                __builtin_amdgcn_s_setprio(1);
                #pragma unroll
                for (int u = 0; u < 4; ++u)
                    #pragma unroll
                    for (int fj = 0; fj < 4; ++fj)
                        acc[fih + u][fj] =
                            __builtin_amdgcn_mfma_scale_f32_16x16x128_f8f6f4(
                                a4[u], b[fj], acc[fih + u][fj],
                                4, 4,          // cbsz = blgp = fp4 (e2m1)
                                0, SCALE1,     // opsel_a, scale_a = 1.0
                                0, SCALE1);    // opsel_b, scale_b = 1.0
                __builtin_amdgcn_s_setprio(0);
            }
        }
        BAR;   // all reads of slot cur done before next iter overwrites it
    }

    // Fused epilogue (column-side only; full grid covers both (i,j),(j,i)).
    // 16x16 C/D layout: col = lane&15, row = (lane>>4)*4 + q.  p = acc/1024.
    int jc[4], tj[4];
    #pragma unroll
    for (int fj = 0; fj < 4; ++fj) {
        jc[fj] = colbase + wc * 64 + fj * 16 + l15;
        tj[fj] = tgt[jc[fj]];
    }
    float denc[4] = {0.f, 0.f, 0.f, 0.f};
    float posc[4] = {0.f, 0.f, 0.f, 0.f};

    #pragma unroll
    for (int fi = 0; fi < 8; ++fi) {
        const int ribase = rowbase + wr * 128 + fi * 16 + (l >> 4) * 4;
        const int4 tiv = *reinterpret_cast<const int4*>(&tgt[ribase]);
        const int tia[4] = {tiv.x, tiv.y, tiv.z, tiv.w};
        #pragma unroll
        for (int q = 0; q < 4; ++q) {
            const int gi = ribase + q;
            const int ti = tia[q];
            #pragma unroll
            for (int fj = 0; fj < 4; ++fj) {
                const float s  = acc[fi][fj][q] * INV_S;
                const float pc = fmaxf(s, 1e-10f);
                const float e  = __expf(TEMP_INV * pc);
                if (ti != tj[fj]) {
                    denc[fj] += e;
                } else if (gi != jc[fj]) {
                    posc[fj] += pc;
                }
            }
        }
    }

    // Lanes sharing a column differ in bits 4-5.
    #pragma unroll
    for (int fj = 0; fj < 4; ++fj) {
        #pragma unroll
        for (int off = 16; off < 64; off <<= 1) {
            denc[fj] += __shfl_xor(denc[fj], off, 64);
            posc[fj] += __shfl_xor(posc[fj], off, 64);
        }
        if (l < 16) {
            atomicAdd(&denw[jc[fj]], denc[fj]);
            atomicAdd(&posw[jc[fj]], posc[fj]);
        }
    }
}

// Single-block finalize: LDS class histogram + per-column loss + direct store.
__global__ __launch_bounds__(1024) void finalize_k(const float* __restrict__ posw,
                                                   const float* __restrict__ denw,
                                                   const int* __restrict__ tgt,
                                                   float* __restrict__ out) {
    __shared__ int hist[128];
    __shared__ float red[16];
    const int tid = threadIdx.x;
    if (tid < 128) hist[tid] = 0;
    __syncthreads();
    const int4 t4 = reinterpret_cast<const int4*>(tgt)[tid];   // 4 targets/thread
    atomicAdd(&hist[t4.x], 1);
    atomicAdd(&hist[t4.y], 1);
    atomicAdd(&hist[t4.z], 1);
    atomicAdd(&hist[t4.w], 1);
    __syncthreads();
    const int ta[4] = {t4.x, t4.y, t4.z, t4.w};
    float v = 0.0f;
    #pragma unroll
    for (int q = 0; q < 4; ++q) {
        const int j = tid * 4 + q;
        const float d = fmaxf(denw[j], 1e-10f);
        const float c = (float)(hist[ta[q]] - 1);
        v += TEMP_INV * posw[j] - c * __logf(d);
    }
    #pragma unroll
    for (int off = 32; off; off >>= 1) v += __shfl_xor(v, off, 64);
    if ((tid & 63) == 0) red[tid >> 6] = v;
    __syncthreads();
    if (tid == 0) {
        float s = 0.0f;
        #pragma unroll
        for (int i = 0; i < 16; ++i) s += red[i];
        out[0] = -s * (1.0f / 4096.0f);
    }
}

extern "C" void kernel_launch(void* const* d_in, const int* in_sizes, int n_in,
                              void* d_out, int out_size, void* d_ws, size_t ws_size,
                              hipStream_t stream) {
    const float* pred = (const float*)d_in[0];
    const int*   tgt  = (const int*)d_in[1];
    float* out = (float*)d_out;

    unsigned short* xn = (unsigned short*)d_ws;                      // 2 MB fp4
    float* posw = (float*)((char*)d_ws + (size_t)NROWS * ROWB);
    float* denw = posw + NROWS;

    normalize_k<<<NROWS, 256, 0, stream>>>(pred, xn, posw, denw);

    fused_gram<<<NTB * NTB, 512, 0, stream>>>(xn, tgt, posw, denw);  // 256 blocks

    finalize_k<<<1, 1024, 0, stream>>>(posw, denw, tgt, out);
}

// Round 15
// 35.510 us; speedup vs baseline: 2.1827x; 2.0652x over previous
//
#include <hip/hip_runtime.h>
#include <hip/hip_bf16.h>

#define NROWS 4096
#define DIM   1024           // K elements; 1024 B/row in int8
#define BT    256            // tile edge (256x256 per block)
#define BK    128            // K-step (128 B = 128 k-elems)
#define NKT   (DIM / BK)     // 8 K-steps
#define NTB   (NROWS / BT)   // 16 tile-blocks per edge
#define TEMP_INV 10.0f
#define INV_S 3.814697e-6f   // 1/(512*512): int8 stored as round(512*x)

typedef int i32x4 __attribute__((ext_vector_type(4)));

__device__ __forceinline__ void gload16(const void* g, void* l) {
    __builtin_amdgcn_global_load_lds(
        (const __attribute__((address_space(1))) void*)g,
        (__attribute__((address_space(3))) void*)l, 16, 0, 0);
}

// Stage one 256x128 int8 K-tile (32 KB) into LDS, 4 x gload16 per thread
// (512 thr).  Byte-identical to the R4/R9/R12 proven staging: linear LDS
// dest (m104), granule swizzle kg = (p&7)^(r&7) pre-applied on the global
// source (rule 21; 0 conflicts verified in R4/R8/R12).
__device__ __forceinline__ void stage_tile(const unsigned char* __restrict__ src,
                                           unsigned char* lds, int tid) {
    #pragma unroll
    for (int c = 0; c < 4; ++c) {
        const int p  = c * 512 + tid;        // granule 0..2047
        const int r  = p >> 3;               // tile row 0..255
        const int kg = (p & 7) ^ (r & 7);    // logical k-granule held at p
        gload16(src + (size_t)r * DIM + kg * 16, lds + p * 16);
    }
}

// Row-normalize fp32 -> int8 (round(512 * x / ||x||), clamp +-127); zeroes
// this row's partial accumulators.  Gaussian rows: max |elem| ~ 5 sigma =
// 0.156 < 127/512 = 0.248, so the clamp is effectively never hit.
__global__ __launch_bounds__(256) void normalize_k(const float* __restrict__ pred,
                                                   unsigned char* __restrict__ xn,
                                                   float* __restrict__ posw,
                                                   float* __restrict__ denw) {
    const int row = blockIdx.x;
    const int tid = threadIdx.x;
    const float4 v = reinterpret_cast<const float4*>(pred + (size_t)row * DIM)[tid];
    float ss = v.x * v.x + v.y * v.y + v.z * v.z + v.w * v.w;
    #pragma unroll
    for (int off = 32; off; off >>= 1) ss += __shfl_xor(ss, off, 64);
    __shared__ float red[4];
    if ((tid & 63) == 0) red[tid >> 6] = ss;
    __syncthreads();
    const float tot = red[0] + red[1] + red[2] + red[3];
    const float scale = 512.0f / fmaxf(sqrtf(tot), 1e-8f);
    int q0 = __float2int_rn(v.x * scale);
    int q1 = __float2int_rn(v.y * scale);
    int q2 = __float2int_rn(v.z * scale);
    int q3 = __float2int_rn(v.w * scale);
    q0 = min(max(q0, -127), 127); q1 = min(max(q1, -127), 127);
    q2 = min(max(q2, -127), 127); q3 = min(max(q3, -127), 127);
    const int pk = (q0 & 0xFF) | ((q1 & 0xFF) << 8) |
                   ((q2 & 0xFF) << 16) | ((q3 & 0xFF) << 24);
    reinterpret_cast<int*>(xn)[row * (DIM / 4) + tid] = pk;
    if (tid == 0) { posw[row] = 0.0f; denw[row] = 0.0f; }
}

#define BAR asm volatile("s_barrier" ::: "memory")

// Fused Gram-GEMM + contrastive epilogue.  Full 16x16 grid (256 blocks,
// 1/CU), 8 waves (2M x 4N), per-wave output 128x64.
// mfma_i32_16x16x64_i8: K=64/instruction at the same per-instruction cost
// as bf16-K=32 (m16) -> 64 MFMA/wave/step, the SAME instruction count as
// R4's ceiling-hitting bf16 kernel, with HALF the staged bytes (131 MB).
// Staging/vmcnt schedule byte-identical to R4 (proven 2.6 us/step at the
// 6.4 TB/s aggregate ingest ceiling, compute fully hidden).
// Layout safety: Gram is k-permutation invariant and the i8 MFMA's A/B
// lane->k maps are symmetric ((l>>4) k-groups, shared byte order), so one
// contiguous 16B ds_read_b128 per fragment is correct by construction.
__global__ __launch_bounds__(512, 2) void fused_gram(
        const unsigned char* __restrict__ xn, const int* __restrict__ tgt,
        float* __restrict__ posw, float* __restrict__ denw) {
    __shared__ unsigned char As[2][BT * BK];   // 2 x 32 KB
    __shared__ unsigned char Bs[2][BT * BK];   // 2 x 32 KB  (128 KB total)

    const int bi = blockIdx.x >> 4;
    const int bj = blockIdx.x & 15;
    const int rowbase = bi * BT;
    const int colbase = bj * BT;

    const int tid = threadIdx.x;
    const int w   = tid >> 6;
    const int l   = tid & 63;
    const int wr  = w >> 2;      // 0..1  (row half: 128 rows)
    const int wc  = w & 3;       // 0..3  (col quarter: 64 cols)
    const int l15 = l & 15;
    const int kgl = l >> 4;      // k-group 0..3 (16 k each per MFMA)

    const unsigned char* arow = xn + (size_t)rowbase * DIM;
    const unsigned char* bcol = xn + (size_t)colbase * DIM;

    // Per-lane LDS byte offsets.  Slice s (k-base 64s) needs logical granule
    // s*4 + kgl of the lane's row; physical = logical ^ (row&7); row&7 ==
    // l15&7 for all our rows (wr/fi/wc/fj terms are multiples of 16).
    int rowA[8], rowB[4], xr[2];
    #pragma unroll
    for (int fi = 0; fi < 8; ++fi) rowA[fi] = (wr * 128 + fi * 16 + l15) * BK;
    #pragma unroll
    for (int fj = 0; fj < 4; ++fj) rowB[fj] = (wc * 64 + fj * 16 + l15) * BK;
    #pragma unroll
    for (int s = 0; s < 2; ++s) xr[s] = ((s * 4 + kgl) ^ (l15 & 7)) * 16;

    i32x4 acc[8][4];
    #pragma unroll
    for (int i = 0; i < 8; ++i)
        #pragma unroll
        for (int j = 0; j < 4; ++j)
            acc[i][j] = (i32x4){0, 0, 0, 0};

    // Prologue: stage K-tile 0 into slot 0 (8 loads/thread).
    stage_tile(arow, &As[0][0], tid);
    stage_tile(bcol, &Bs[0][0], tid);

    for (int kt = 0; kt < NKT; ++kt) {
        const int cur = kt & 1;
        if (kt + 1 < NKT) {
            stage_tile(arow + (kt + 1) * BK, &As[cur ^ 1][0], tid);
            stage_tile(bcol + (kt + 1) * BK, &Bs[cur ^ 1][0], tid);
            asm volatile("s_waitcnt vmcnt(8)" ::: "memory");   // tile kt landed
        } else {
            asm volatile("s_waitcnt vmcnt(0)" ::: "memory");
        }
        BAR;

        const unsigned char* as = &As[cur][0];
        const unsigned char* bs = &Bs[cur][0];
        #pragma unroll
        for (int s = 0; s < 2; ++s) {        // two K=64 slices per staged step
            i32x4 a[8], b[4];
            #pragma unroll
            for (int fi = 0; fi < 8; ++fi)
                a[fi] = *reinterpret_cast<const i32x4*>(&as[rowA[fi] + xr[s]]);
            #pragma unroll
            for (int fj = 0; fj < 4; ++fj)
                b[fj] = *reinterpret_cast<const i32x4*>(&bs[rowB[fj] + xr[s]]);
            __builtin_amdgcn_s_setprio(1);
            #pragma unroll
            for (int fi = 0; fi < 8; ++fi)
                #pragma unroll
                for (int fj = 0; fj < 4; ++fj)
                    acc[fi][fj] = __builtin_amdgcn_mfma_i32_16x16x64_i8(
                        a[fi], b[fj], acc[fi][fj], 0, 0, 0);
            __builtin_amdgcn_s_setprio(0);
        }
        BAR;   // all reads of slot cur done before next iter overwrites it
    }

    // Fused epilogue (column-side only; full grid covers both (i,j),(j,i)).
    // 16x16 C/D layout: col = lane&15, row = (lane>>4)*4 + q (dtype-
    // independent, m89/m121).  p = acc / 512^2.
    int jc[4], tj[4];
    #pragma unroll
    for (int fj = 0; fj < 4; ++fj) {
        jc[fj] = colbase + wc * 64 + fj * 16 + l15;
        tj[fj] = tgt[jc[fj]];
    }
    float denc[4] = {0.f, 0.f, 0.f, 0.f};
    float posc[4] = {0.f, 0.f, 0.f, 0.f};

    #pragma unroll
    for (int fi = 0; fi < 8; ++fi) {
        const int ribase = rowbase + wr * 128 + fi * 16 + (l >> 4) * 4;
        const int4 tiv = *reinterpret_cast<const int4*>(&tgt[ribase]);
        const int tia[4] = {tiv.x, tiv.y, tiv.z, tiv.w};
        #pragma unroll
        for (int q = 0; q < 4; ++q) {
            const int gi = ribase + q;
            const int ti = tia[q];
            #pragma unroll
            for (int fj = 0; fj < 4; ++fj) {
                const float s  = (float)acc[fi][fj][q] * INV_S;
                const float pc = fmaxf(s, 1e-10f);
                const float e  = __expf(TEMP_INV * pc);
                if (ti != tj[fj]) {
                    denc[fj] += e;
                } else if (gi != jc[fj]) {
                    posc[fj] += pc;
                }
            }
        }
    }

    // Lanes sharing a column differ in bits 4-5.
    #pragma unroll
    for (int fj = 0; fj < 4; ++fj) {
        #pragma unroll
        for (int off = 16; off < 64; off <<= 1) {
            denc[fj] += __shfl_xor(denc[fj], off, 64);
            posc[fj] += __shfl_xor(posc[fj], off, 64);
        }
        if (l < 16) {
            atomicAdd(&denw[jc[fj]], denc[fj]);
            atomicAdd(&posw[jc[fj]], posc[fj]);
        }
    }
}

// Single-block finalize: LDS class histogram + per-column loss + direct store.
__global__ __launch_bounds__(1024) void finalize_k(const float* __restrict__ posw,
                                                   const float* __restrict__ denw,
                                                   const int* __restrict__ tgt,
                                                   float* __restrict__ out) {
    __shared__ int hist[128];
    __shared__ float red[16];
    const int tid = threadIdx.x;
    if (tid < 128) hist[tid] = 0;
    __syncthreads();
    const int4 t4 = reinterpret_cast<const int4*>(tgt)[tid];   // 4 targets/thread
    atomicAdd(&hist[t4.x], 1);
    atomicAdd(&hist[t4.y], 1);
    atomicAdd(&hist[t4.z], 1);
    atomicAdd(&hist[t4.w], 1);
    __syncthreads();
    const int ta[4] = {t4.x, t4.y, t4.z, t4.w};
    float v = 0.0f;
    #pragma unroll
    for (int q = 0; q < 4; ++q) {
        const int j = tid * 4 + q;
        const float d = fmaxf(denw[j], 1e-10f);
        const float c = (float)(hist[ta[q]] - 1);
        v += TEMP_INV * posw[j] - c * __logf(d);
    }
    #pragma unroll
    for (int off = 32; off; off >>= 1) v += __shfl_xor(v, off, 64);
    if ((tid & 63) == 0) red[tid >> 6] = v;
    __syncthreads();
    if (tid == 0) {
        float s = 0.0f;
        #pragma unroll
        for (int i = 0; i < 16; ++i) s += red[i];
        out[0] = -s * (1.0f / 4096.0f);
    }
}

extern "C" void kernel_launch(void* const* d_in, const int* in_sizes, int n_in,
                              void* d_out, int out_size, void* d_ws, size_t ws_size,
                              hipStream_t stream) {
    const float* pred = (const float*)d_in[0];
    const int*   tgt  = (const int*)d_in[1];
    float* out = (float*)d_out;

    unsigned char* xn = (unsigned char*)d_ws;                        // 4 MB int8
    float* posw = (float*)((char*)d_ws + (size_t)NROWS * DIM);
    float* denw = posw + NROWS;

    normalize_k<<<NROWS, 256, 0, stream>>>(pred, xn, posw, denw);

    fused_gram<<<NTB * NTB, 512, 0, stream>>>(xn, tgt, posw, denw);  // 256 blocks

    finalize_k<<<1, 1024, 0, stream>>>(posw, denw, tgt, out);
}